// Round 2
// baseline (517.590 us; speedup 1.0000x reference)
//
#include <hip/hip_runtime.h>
#include <cstddef>

#define N 1024
#define DN 128      // NODE_DIM
#define DE 16       // EDGE_DIM
#define DM 64       // MSG_DIM
#define TSTEPS 3
#define INDIM 272   // 2*DN + DE

// ---------------------------------------------------------------------------
// Kernel A (2 rows/block): P[i,0:64]=hi, P[i,64:128]=hj, P[i,128:512]=gh+b_hh
// ---------------------------------------------------------------------------
__global__ __launch_bounds__(256) void kA(const float* __restrict__ H,
                                          const float* __restrict__ W1,
                                          const float* __restrict__ W_hh,
                                          const float* __restrict__ b_hh,
                                          float* __restrict__ P) {
  int i0 = blockIdx.x * 2;
  int t = threadIdx.x;
  __shared__ float h[2][DN];
  if (t < 2 * DN) h[t >> 7][t & 127] = H[(size_t)i0 * DN + t];
  __syncthreads();
  for (int c = t; c < 512; c += 256) {
    const float* w;
    float bias;
    if (c < 64)       { w = W1 + c * INDIM;              bias = 0.f; }
    else if (c < 128) { w = W1 + (c - 64) * INDIM + 128; bias = 0.f; }
    else              { w = W_hh + (c - 128) * DN;       bias = b_hh[c - 128]; }
    const float4* w4 = (const float4*)w;
    float a0 = bias, a1 = bias;
    #pragma unroll
    for (int k4 = 0; k4 < DN / 4; ++k4) {
      float4 wv = w4[k4];
      a0 = fmaf(h[0][k4 * 4 + 0], wv.x, a0);
      a1 = fmaf(h[1][k4 * 4 + 0], wv.x, a1);
      a0 = fmaf(h[0][k4 * 4 + 1], wv.y, a0);
      a1 = fmaf(h[1][k4 * 4 + 1], wv.y, a1);
      a0 = fmaf(h[0][k4 * 4 + 2], wv.z, a0);
      a1 = fmaf(h[1][k4 * 4 + 2], wv.z, a1);
      a0 = fmaf(h[0][k4 * 4 + 3], wv.w, a0);
      a1 = fmaf(h[1][k4 * 4 + 3], wv.w, a1);
    }
    P[(size_t)i0 * 512 + c]       = a0;
    P[(size_t)(i0 + 1) * 512 + c] = a1;
  }
}

// ---------------------------------------------------------------------------
// Kernel B (1024 threads/block, j split 64-ways):
//   S[i,m] = sum_j A[i,j]*relu(hi[i,m]+hj[j,m]+Ep[i,j,m]+b1[m]);  deg[i]=sum_j A
// Ep on the fly from E[i,j,:] @ We.T. mq = t&15 (m-quad), jj = t>>4 (0..63).
// ---------------------------------------------------------------------------
__global__ __launch_bounds__(1024) void kB(const float* __restrict__ P,
                                           const float* __restrict__ E,
                                           const float* __restrict__ W1,
                                           const float* __restrict__ b1,
                                           const int* __restrict__ A,
                                           float* __restrict__ S,
                                           float* __restrict__ deg) {
  int i  = blockIdx.x;
  int t  = threadIdx.x;
  int mq = t & 15;   // m-quad: m = 4*mq .. 4*mq+3
  int jj = t >> 4;   // 0..63

  float we[4][16];
  #pragma unroll
  for (int mi = 0; mi < 4; ++mi) {
    const float4* wr4 = (const float4*)(W1 + (size_t)(mq * 4 + mi) * INDIM + 256);
    #pragma unroll
    for (int q = 0; q < 4; ++q) {
      float4 v = wr4[q];
      we[mi][q * 4 + 0] = v.x;
      we[mi][q * 4 + 1] = v.y;
      we[mi][q * 4 + 2] = v.z;
      we[mi][q * 4 + 3] = v.w;
    }
  }

  float hib[4];
  #pragma unroll
  for (int mi = 0; mi < 4; ++mi)
    hib[mi] = P[(size_t)i * 512 + mq * 4 + mi] + b1[mq * 4 + mi];

  float s[4] = {0.f, 0.f, 0.f, 0.f};
  int degp = 0;

  const float* Erow = E + (size_t)i * N * DE;
  const int*   Arow = A + (size_t)i * N;

  #pragma unroll 2
  for (int jt = 0; jt < N / 64; ++jt) {
    int j = jt * 64 + jj;

    const float4* e4 = (const float4*)(Erow + (size_t)j * DE);
    float4 q0 = e4[0], q1 = e4[1], q2 = e4[2], q3 = e4[3];

    float4 hj4 = *(const float4*)(P + (size_t)j * 512 + 64 + mq * 4);
    int   a  = Arow[j];
    float af = (float)a;
    if (mq == 0) degp += a;

    float ep[4];
    #pragma unroll
    for (int mi = 0; mi < 4; ++mi) {
      float acc;
      acc = q0.x * we[mi][0];
      acc = fmaf(q0.y, we[mi][1], acc);
      acc = fmaf(q0.z, we[mi][2], acc);
      acc = fmaf(q0.w, we[mi][3], acc);
      acc = fmaf(q1.x, we[mi][4], acc);
      acc = fmaf(q1.y, we[mi][5], acc);
      acc = fmaf(q1.z, we[mi][6], acc);
      acc = fmaf(q1.w, we[mi][7], acc);
      acc = fmaf(q2.x, we[mi][8], acc);
      acc = fmaf(q2.y, we[mi][9], acc);
      acc = fmaf(q2.z, we[mi][10], acc);
      acc = fmaf(q2.w, we[mi][11], acc);
      acc = fmaf(q3.x, we[mi][12], acc);
      acc = fmaf(q3.y, we[mi][13], acc);
      acc = fmaf(q3.z, we[mi][14], acc);
      acc = fmaf(q3.w, we[mi][15], acc);
      ep[mi] = acc;
    }

    float pre0 = hib[0] + hj4.x + ep[0];
    float pre1 = hib[1] + hj4.y + ep[1];
    float pre2 = hib[2] + hj4.z + ep[2];
    float pre3 = hib[3] + hj4.w + ep[3];
    s[0] = fmaf(af, fmaxf(pre0, 0.f), s[0]);
    s[1] = fmaf(af, fmaxf(pre1, 0.f), s[1]);
    s[2] = fmaf(af, fmaxf(pre2, 0.f), s[2]);
    s[3] = fmaf(af, fmaxf(pre3, 0.f), s[3]);
  }

  __shared__ float red[64][DM];
  __shared__ float dred[64];
  *(float4*)&red[jj][mq * 4] = make_float4(s[0], s[1], s[2], s[3]);
  if (mq == 0) dred[jj] = (float)degp;
  __syncthreads();

  if (t < DM) {
    float acc = 0.f;
    #pragma unroll
    for (int r = 0; r < 64; ++r) acc += red[r][t];
    S[(size_t)i * DM + t] = acc;
  }
  if (t == DM) {
    float d = 0.f;
    #pragma unroll
    for (int r = 0; r < 64; ++r) d += dred[r];
    deg[i] = d;
  }
}

// ---------------------------------------------------------------------------
// Kernel C (2 rows/block): M = S@W2.T + deg*b2; gi = M@W_ih.T + b_ih; GRU.
// ---------------------------------------------------------------------------
__global__ __launch_bounds__(256) void kC(const float* __restrict__ P,
                                          const float* __restrict__ S,
                                          const float* __restrict__ deg,
                                          const float* __restrict__ W2,
                                          const float* __restrict__ b2,
                                          const float* __restrict__ W_ih,
                                          const float* __restrict__ b_ih,
                                          const float* __restrict__ Hin,
                                          float* __restrict__ Hout) {
  int i0 = blockIdx.x * 2;
  int t = threadIdx.x;
  __shared__ float sS[2][DM];
  __shared__ float sM[2][DM];
  __shared__ float sGi[2][384];

  if (t < 2 * DM) sS[t >> 6][t & 63] = S[(size_t)i0 * DM + t];
  __syncthreads();

  if (t < 2 * DM) {
    int ii = t >> 6, m = t & 63;
    float acc = deg[i0 + ii] * b2[m];
    const float4* w4 = (const float4*)(W2 + (size_t)m * DM);
    #pragma unroll
    for (int k4 = 0; k4 < DM / 4; ++k4) {
      float4 wv = w4[k4];
      acc = fmaf(sS[ii][k4 * 4 + 0], wv.x, acc);
      acc = fmaf(sS[ii][k4 * 4 + 1], wv.y, acc);
      acc = fmaf(sS[ii][k4 * 4 + 2], wv.z, acc);
      acc = fmaf(sS[ii][k4 * 4 + 3], wv.w, acc);
    }
    sM[ii][m] = acc;
  }
  __syncthreads();

  for (int c = t; c < 384; c += 256) {
    float b = b_ih[c];
    float a0 = b, a1 = b;
    const float4* w4 = (const float4*)(W_ih + (size_t)c * DM);
    #pragma unroll
    for (int k4 = 0; k4 < DM / 4; ++k4) {
      float4 wv = w4[k4];
      a0 = fmaf(sM[0][k4 * 4 + 0], wv.x, a0);
      a1 = fmaf(sM[1][k4 * 4 + 0], wv.x, a1);
      a0 = fmaf(sM[0][k4 * 4 + 1], wv.y, a0);
      a1 = fmaf(sM[1][k4 * 4 + 1], wv.y, a1);
      a0 = fmaf(sM[0][k4 * 4 + 2], wv.z, a0);
      a1 = fmaf(sM[1][k4 * 4 + 2], wv.z, a1);
      a0 = fmaf(sM[0][k4 * 4 + 3], wv.w, a0);
      a1 = fmaf(sM[1][k4 * 4 + 3], wv.w, a1);
    }
    sGi[0][c] = a0;
    sGi[1][c] = a1;
  }
  __syncthreads();

  {
    int ii = t >> 7, tt = t & 127;
    int i = i0 + ii;
    float ghr = P[(size_t)i * 512 + 128 + tt];
    float ghz = P[(size_t)i * 512 + 256 + tt];
    float ghn = P[(size_t)i * 512 + 384 + tt];
    float gir = sGi[ii][tt], giz = sGi[ii][128 + tt], gin = sGi[ii][256 + tt];
    float r = 1.f / (1.f + expf(-(gir + ghr)));
    float z = 1.f / (1.f + expf(-(giz + ghz)));
    float n = tanhf(gin + r * ghn);
    float h = Hin[(size_t)i * DN + tt];
    Hout[(size_t)i * DN + tt] = (1.f - z) * n + z * h;
  }
}

// ---------------------------------------------------------------------------
extern "C" void kernel_launch(void* const* d_in, const int* in_sizes, int n_in,
                              void* d_out, int out_size, void* d_ws, size_t ws_size,
                              hipStream_t stream) {
  const float* X    = (const float*)d_in[0];
  const int*   A    = (const int*)  d_in[1];
  const float* E    = (const float*)d_in[2];
  const float* W1   = (const float*)d_in[3];
  const float* b1   = (const float*)d_in[4];
  const float* W2   = (const float*)d_in[5];
  const float* b2   = (const float*)d_in[6];
  const float* W_ih = (const float*)d_in[7];
  const float* b_ih = (const float*)d_in[8];
  const float* W_hh = (const float*)d_in[9];
  const float* b_hh = (const float*)d_in[10];
  float* out = (float*)d_out;

  float* ws   = (float*)d_ws;
  float* Hbuf = ws;                    // N*DN  floats
  float* P    = Hbuf + N * DN;         // N*512 floats
  float* S    = P + N * 512;           // N*DM  floats
  float* deg  = S + N * DM;            // N     floats

  hipMemcpyAsync(Hbuf, X, (size_t)N * DN * sizeof(float),
                 hipMemcpyDeviceToDevice, stream);

  for (int step = 0; step < TSTEPS; ++step) {
    kA<<<N / 2, 256, 0, stream>>>(Hbuf, W1, W_hh, b_hh, P);
    kB<<<N, 1024, 0, stream>>>(P, E, W1, b1, A, S, deg);
    float* Hout = (step == TSTEPS - 1) ? out : Hbuf;
    kC<<<N / 2, 256, 0, stream>>>(P, S, deg, W2, b2, W_ih, b_ih, Hbuf, Hout);
  }
}